// Round 10
// baseline (472.370 us; speedup 1.0000x reference)
//
#include <hip/hip_runtime.h>
#include <cstdint>

#define T_SEQ 40
#define NB    16384
#define NH    128
#define ZSTR  168            // bf16 elems per z-tile row (160 used)
#define GROWS 16             // batch rows per block
#define NTHR  256            // 4 waves; wave w owns neuron cols [32w, 32w+32)
#define NBLK  (NB / GROWS)   // 1024 blocks

typedef float v4f __attribute__((ext_vector_type(4)));
typedef short v8s __attribute__((ext_vector_type(8)));

// RNE float->bf16 bits; w == b1+b2+b3 exactly (24-bit mantissa = 3x8)
__device__ __forceinline__ unsigned short f2bf(float f) {
  uint32_t u = __float_as_uint(f);
  return (unsigned short)((u + 0x7FFFu + ((u >> 16) & 1u)) >> 16);
}
__device__ __forceinline__ float bf2f(unsigned short b) {
  return __uint_as_float(((uint32_t)b) << 16);
}
template <int C>
__device__ __forceinline__ float dppadd(float v) {
  int t = __builtin_amdgcn_update_dpp(0, __float_as_int(v), C, 0xF, 0xF, true);
  return v + __int_as_float(t);
}
__device__ __forceinline__ float red16(float v) {   // sum within each 16-lane DPP row
  v = dppadd<0x111>(v);
  v = dppadd<0x112>(v);
  v = dppadd<0x114>(v);
  v = dppadd<0x118>(v);
  return v;                                          // lane q*16+15 holds the sum
}

__global__ __launch_bounds__(NTHR, 2)
void Policy_22033182228693_kernel(const float* __restrict__ x,
                                  const float* __restrict__ w_in,
                                  const float* __restrict__ w_rec,
                                  const float* __restrict__ w_out,
                                  const float* __restrict__ dmask,
                                  float* __restrict__ out)
{
  __shared__ unsigned short Z[2][GROWS * ZSTR];    // [z(128)|xs(8)|pad] bf16, dbuf (10.75 KB)
  __shared__ unsigned short XS[T_SEQ * 128];       // encoder spikes [t][batch*8+ch] (10.25 KB)
  __shared__ float MB[2][GROWS * NH];              // dropout step-slab, dbuf (16 KB)
  __shared__ float UP[T_SEQ][4][GROWS][2];         // per-step readout partials (20.5 KB)

  const int tid  = threadIdx.x;
  const int wv   = tid >> 6;
  const int lane = tid & 63;
  const int m    = lane & 15;     // MFMA 16-index
  const int q    = lane >> 4;     // quad
  const int wcol = wv * 32;
  const int gb   = blockIdx.x * GROWS;
  const size_t TS = (size_t)NB * NH;

  // ---- B-frags, register-resident, loaded as float4 pairs (coalesced-ish: 20 wide loads,
  // each instr's 16B/lane segments cluster 4-per-128B-line -> ~16 txns/instr vs 64) ----
  v8s bfr[2][5][3];
#pragma unroll
  for (int tau = 0; tau < 2; ++tau) {
    const int n = wcol + tau * 16 + m;
#pragma unroll
    for (int c = 0; c < 5; ++c) {
      const int kb = c * 32 + q * 8;
      float w8[8];
      if (c < 4) {
        float4 wa = *(const float4*)&w_rec[n * NH + kb];
        float4 wb = *(const float4*)&w_rec[n * NH + kb + 4];
        w8[0]=wa.x; w8[1]=wa.y; w8[2]=wa.z; w8[3]=wa.w;
        w8[4]=wb.x; w8[5]=wb.y; w8[6]=wb.z; w8[7]=wb.w;
      } else if (q == 0) {                       // k = 128..135 -> w_in
        float4 wa = *(const float4*)&w_in[n * 8];
        float4 wb = *(const float4*)&w_in[n * 8 + 4];
        w8[0]=wa.x; w8[1]=wa.y; w8[2]=wa.z; w8[3]=wa.w;
        w8[4]=wb.x; w8[5]=wb.y; w8[6]=wb.z; w8[7]=wb.w;
      } else {                                   // k = 136..159 -> zero pad
#pragma unroll
        for (int j = 0; j < 8; ++j) w8[j] = 0.f;
      }
      union { v8s v; unsigned short u[8]; } f0, f1, f2;
#pragma unroll
      for (int j = 0; j < 8; ++j) {
        float w = w8[j];
        unsigned short b1 = f2bf(w);  float r1 = w - bf2f(b1);
        unsigned short b2 = f2bf(r1); float r2 = r1 - bf2f(b2);
        unsigned short b3 = f2bf(r2);
        f0.u[j] = b1; f1.u[j] = b2; f2.u[j] = b3;
      }
      bfr[tau][c][0] = f0.v; bfr[tau][c][1] = f1.v; bfr[tau][c][2] = f2.v;
    }
  }

  // readout weights for this lane's two columns
  const float wo00 = w_out[wcol + m],      wo01 = w_out[wcol + 16 + m];
  const float wo10 = w_out[NH + wcol + m], wo11 = w_out[NH + wcol + 16 + m];

  // zero both z-tile buffers once
  for (int e = tid; e < 2 * GROWS * ZSTR; e += NTHR) ((unsigned short*)Z)[e] = 0;
  __syncthreads();

  // ---- encoder precompute (threads 0..127) + t=0 mask slab staging (all threads) ----
  const int srow = tid >> 4;                 // 0..15
  const int scol = (tid & 15) * 8;           // 0..120 step 8
  {
    const float* g0 = dmask + (size_t)(gb + srow) * NH + scol;   // t=0 slab
    float4 p0 = *(const float4*)g0;
    float4 p1 = *(const float4*)(g0 + 4);
    if (tid < 128) {
      const int bi = tid >> 3, ch = tid & 7;
      float xv = x[(size_t)(gb + bi) * 4 + (ch & 3)];
      float cc = fmaxf(0.f, ((ch & 4) ? -50.f : 50.f) * xv);
      float ve = 0.f;
      for (int t = 0; t < T_SEQ; ++t) {
        ve += 0.1f * (cc - ve);
        unsigned short zb = 0;
        if (ve > 1.0f) { zb = 0x3F80; ve = 0.f; }
        XS[t * 128 + tid] = zb;
        if (t == 0) Z[0][bi * ZSTR + NH + ch] = zb;
      }
    }
    float* mrow = &MB[0][srow * NH + scol];
    *(float4*)mrow = p0;
    *(float4*)(mrow + 4) = p1;
  }
  __syncthreads();

  v4f iacc[2] = {{0,0,0,0},{0,0,0,0}};
  v4f vmem[2] = {{0,0,0,0},{0,0,0,0}};
  int pb = 0;

#pragma unroll 1
  for (int t = 0; t < T_SEQ; ++t) {
    // ---- prefetch next step's mask slab (fully coalesced float4 pair) ----
    const int tn = (t + 1 < T_SEQ) ? t + 1 : T_SEQ - 1;
    const float* gs = dmask + (size_t)tn * TS + (size_t)(gb + srow) * NH + scol;
    float4 npf0 = *(const float4*)gs;
    float4 npf1 = *(const float4*)(gs + 4);

    // ---- A-frags from Z[pb] ----
    v8s af[5];
    const unsigned short* zrow = &Z[pb][m * ZSTR];
#pragma unroll
    for (int c = 0; c < 5; ++c) af[c] = *(const v8s*)(zrow + c * 32 + q * 8);

    // ---- membrane from OLD i (C-layout: row=q*4+r, col=wcol+tau*16+m) ----
    float zf[2][4];
#pragma unroll
    for (int tau = 0; tau < 2; ++tau) {
      v4f vd = vmem[tau] + 0.1f * (iacc[tau] - vmem[tau]);
#pragma unroll
      for (int r = 0; r < 4; ++r) {
        bool z = vd[r] > 1.0f;
        zf[tau][r] = z ? 1.0f : 0.0f;
        vmem[tau][r] = z ? 0.0f : vd[r];
      }
    }

    // ---- i_new = 0.8*i_old + [z|xs] @ W^T : 6 independent chains of 5 MFMAs ----
    v4f s00 = 0.8f * iacc[0], s01 = {0,0,0,0}, s02 = {0,0,0,0};
    v4f s10 = 0.8f * iacc[1], s11 = {0,0,0,0}, s12 = {0,0,0,0};
#pragma unroll
    for (int c = 0; c < 5; ++c) {
      s00 = __builtin_amdgcn_mfma_f32_16x16x32_bf16(af[c], bfr[0][c][0], s00, 0, 0, 0);
      s10 = __builtin_amdgcn_mfma_f32_16x16x32_bf16(af[c], bfr[1][c][0], s10, 0, 0, 0);
      s01 = __builtin_amdgcn_mfma_f32_16x16x32_bf16(af[c], bfr[0][c][1], s01, 0, 0, 0);
      s11 = __builtin_amdgcn_mfma_f32_16x16x32_bf16(af[c], bfr[1][c][1], s11, 0, 0, 0);
      s02 = __builtin_amdgcn_mfma_f32_16x16x32_bf16(af[c], bfr[0][c][2], s02, 0, 0, 0);
      s12 = __builtin_amdgcn_mfma_f32_16x16x32_bf16(af[c], bfr[1][c][2], s12, 0, 0, 0);
    }
    iacc[0] = (s00 + s01) + s02;
    iacc[1] = (s10 + s11) + s12;

    // ---- z_new into the other buffer ----
    unsigned short* zq = &Z[pb ^ 1][0];
#pragma unroll
    for (int tau = 0; tau < 2; ++tau)
#pragma unroll
      for (int r = 0; r < 4; ++r)
        zq[(q * 4 + r) * ZSTR + wcol + tau * 16 + m] = (zf[tau][r] != 0.f) ? 0x3F80 : 0;

    // xs[t+1] into the other buffer (threads 128..255)
    if (t + 1 < T_SEQ && tid >= 128) {
      const int u = tid - 128;
      Z[pb ^ 1][(u >> 3) * ZSTR + NH + (u & 7)] = XS[(t + 1) * 128 + u];
    }

    // ---- readout partials (off critical path; consumed after the loop) ----
#pragma unroll
    for (int r = 0; r < 4; ++r) {
      float mk0 = MB[t & 1][(q * 4 + r) * NH + wcol + m];
      float mk1 = MB[t & 1][(q * 4 + r) * NH + wcol + 16 + m];
      float zd0 = zf[0][r] * mk0;
      float zd1 = zf[1][r] * mk1;
      float p0 = zd0 * wo00 + zd1 * wo01;
      float p1 = zd0 * wo10 + zd1 * wo11;
      p0 = red16(p0);
      p1 = red16(p1);
      if (m == 15) {
        UP[t][wv][q * 4 + r][0] = p0;
        UP[t][wv][q * 4 + r][1] = p1;
      }
    }

    // ---- commit prefetched mask slab for step t+1 ----
    {
      float* mrow = &MB[(t + 1) & 1][srow * NH + scol];
      *(float4*)mrow = npf0;
      *(float4*)(mrow + 4) = npf1;
    }

    __syncthreads();   // one barrier per step
    pb ^= 1;
  }

  // ---- LI readout scan, once (threads 0..31: row = tid>>1, o = tid&1) ----
  if (tid < 32) {
    const int row = tid >> 1, o = tid & 1;
    float io = 0.f, vo = 0.f, mx = -3.0e38f;
#pragma unroll 1
    for (int t = 0; t < T_SEQ; ++t) {
      float u = ((UP[t][0][row][o] + UP[t][1][row][o])
               +  UP[t][2][row][o]) + UP[t][3][row][o];
      float von = vo + 0.1f * (io - vo);   // uses old io
      io = 0.8f * io + u;
      vo = von;
      mx = fmaxf(mx, vo);
    }
    float other = __shfl_xor(mx, 1);
    if (o == 0) {
      float mxx = fmaxf(mx, other);
      float e0 = expf(mx - mxx), e1 = expf(other - mxx);
      float inv = 1.f / (e0 + e1);
      ((float2*)out)[gb + row] = make_float2(e0 * inv, e1 * inv);
    }
  }
}

extern "C" void kernel_launch(void* const* d_in, const int* in_sizes, int n_in,
                              void* d_out, int out_size, void* d_ws, size_t ws_size,
                              hipStream_t stream) {
  const float* x     = (const float*)d_in[0];
  const float* w_in  = (const float*)d_in[1];
  const float* w_rec = (const float*)d_in[2];
  const float* w_out = (const float*)d_in[3];
  const float* dmask = (const float*)d_in[4];
  float* out = (float*)d_out;

  hipLaunchKernelGGL(Policy_22033182228693_kernel, dim3(NBLK), dim3(NTHR), 0, stream,
                     x, w_in, w_rec, w_out, dmask, out);
}